// Round 8
// baseline (75.022 us; speedup 1.0000x reference)
//
#include <hip/hip_runtime.h>

// Chamfer via MFMA, round 8: register-safe + memory-lean + self-measuring.
// w(i,j) = q.t - 0.5|q|^2 - 0.5|t|^2 = -d^2/2; NN dist^2 = -2 * max_j w.
// Reps stored TILED: [tile(32 pts)][k-half][point][8 bf16] so that
//   - A-fragment load = contiguous coalesced 16B/lane,
//   - LDS fragment read = 16B-stride across lanes (2-way bank alias = free),
//   - global_load_lds stages the chunk linearly (layout preserved).
// 512-thr blocks: 8 waves x 2 i-tiles; j-tiles in pairs: 4 MFMA + 32 v_max3
// per pair, ~106 live VGPR (mrow 32 + acc<=32 sched'd + zero 16 + u 8 + af 8
// + addr) -> no spills under __launch_bounds__(512,4) (128 cap).
// B-traffic: 1024 blocks x 32 KB = 34 MB. NJ=8 chunks merged via atomicMax
// on order-encoded u32 (deterministic). Main kernel launched TWICE
// (idempotent) to measure its duration from total: main = (total - ~11us)/2.
// bf16 hi/lo rep (validated rounds 3-7, absmax 0):
//   A(q) = [qh(3), ql(3), qh(3), hq_h, hq_l,  1,  1, 0,0,0]
//   B(t) = [th(3), th(3), tl(3),  -1,  -1, -ht_h, -ht_l, 0,0,0]

#define NPTS    8192
#define BATCH   4
#define NJ      8
#define JCHUNK  1024               // targets per staged chunk (32 tiles, 32 KB)
#define JTILES  (JCHUNK / 32)      // 32
#define ITB     16                 // i-tiles per block = 8 waves x 2
#define NSLOTS  (2 * BATCH * NPTS) // 65536

typedef __attribute__((ext_vector_type(8))) short short8v;
typedef __attribute__((ext_vector_type(16))) float f32x16;

__device__ __forceinline__ unsigned enc_f32(float f) {
  unsigned u = __float_as_uint(f);
  return (u & 0x80000000u) ? ~u : (u | 0x80000000u);
}
__device__ __forceinline__ float dec_f32(unsigned u) {
  u = (u & 0x80000000u) ? (u ^ 0x80000000u) : ~u;
  return __uint_as_float(u);
}
__device__ __forceinline__ unsigned short f2bf(float x) {   // RNE bf16
  unsigned u = __float_as_uint(x);
  unsigned r = u + 0x7FFFu + ((u >> 16) & 1u);
  return (unsigned short)(r >> 16);
}
__device__ __forceinline__ float bf2f(unsigned short b) {
  return __uint_as_float((unsigned)b << 16);
}

// Tiled element offset for point j (within batch b), half h:
//   b*131072 + (j>>5)*512 + h*256 + (j&31)*8   [unsigned short units]
__global__ __launch_bounds__(256) void prep(
    const float* __restrict__ c1, const float* __restrict__ c2,
    unsigned short* __restrict__ a1, unsigned short* __restrict__ a2,
    unsigned short* __restrict__ b1, unsigned short* __restrict__ b2,
    unsigned* __restrict__ rowbuf) {
  int pid = blockIdx.x * 256 + threadIdx.x;
  if (pid >= BATCH * NPTS) return;
  rowbuf[pid] = 0u;                    // below enc of any real float
  rowbuf[pid + BATCH * NPTS] = 0u;
  const unsigned short one = 0x3F80u, negone = 0xBF80u;
  int b = pid >> 13, j = pid & (NPTS - 1);
  size_t off0 = (size_t)b * 131072 + (size_t)(j >> 5) * 512 + (size_t)(j & 31) * 8;
  const float* cs[2] = {c1, c2};
  unsigned short* as[2] = {a1, a2};
  unsigned short* bs[2] = {b1, b2};
  #pragma unroll
  for (int c = 0; c < 2; ++c) {
    float x = cs[c][pid * 3 + 0], y = cs[c][pid * 3 + 1], z = cs[c][pid * 3 + 2];
    unsigned short xh = f2bf(x), yh = f2bf(y), zh = f2bf(z);
    unsigned short xl = f2bf(x - bf2f(xh)), yl = f2bf(y - bf2f(yh)),
                   zl = f2bf(z - bf2f(zh));
    float hn = 0.5f * (x * x + y * y + z * z);
    unsigned short hh = f2bf(hn), hl = f2bf(hn - bf2f(hh));
    unsigned short va[16] = {xh, yh, zh, xl, yl, zl, xh, yh, zh,
                             hh, hl, one, one, 0, 0, 0};
    unsigned short nh = hh ^ 0x8000u, nl = hl ^ 0x8000u;
    unsigned short vb[16] = {xh, yh, zh, xh, yh, zh, xl, yl, zl,
                             negone, negone, nh, nl, 0, 0, 0};
    *(uint4*)(as[c] + off0)       = *(const uint4*)&va[0];
    *(uint4*)(as[c] + off0 + 256) = *(const uint4*)&va[8];
    *(uint4*)(bs[c] + off0)       = *(const uint4*)&vb[0];
    *(uint4*)(bs[c] + off0 + 256) = *(const uint4*)&vb[8];
  }
}

// grid = 2(dir) x 4(b) x 16(igrp of 512 rows) x 8(jc) = 1024 blocks x 8 waves.
__global__ __launch_bounds__(512, 4) void chamfer_mfma(
    const unsigned short* __restrict__ a1, const unsigned short* __restrict__ a2,
    const unsigned short* __restrict__ b1, const unsigned short* __restrict__ b2,
    unsigned* __restrict__ rowbuf) {
  __shared__ __align__(16) unsigned short sB[JCHUNK * 16];  // 32 KB

  int bid = blockIdx.x;
  int jc  = bid & (NJ - 1);
  int ig  = (bid >> 3) & 15;
  int b   = (bid >> 7) & 3;
  int dir = bid >> 9;

  const unsigned short* A = dir ? a2 : a1;   // queries (tiled rep)
  const unsigned short* B = dir ? b1 : b2;   // targets (tiled rep)

  int wave = threadIdx.x >> 6;
  int lane = threadIdx.x & 63;
  int p = lane & 31, h = lane >> 5;

  // ---- stage 32 KB chunk linearly: 8 waves x 4 x (64 lanes x 16 B) ----
  {
    const char* gb = (const char*)B + (size_t)b * 262144 + (size_t)jc * 32768
                     + wave * 4096 + lane * 16;
    char* lb = (char*)sB + wave * 4096;   // wave-uniform dest (HW adds lane*16)
    #pragma unroll
    for (int k = 0; k < 4; ++k) {
      __builtin_amdgcn_global_load_lds(
          (const __attribute__((address_space(1))) unsigned int*)(gb + k * 1024),
          (__attribute__((address_space(3))) unsigned int*)(lb + k * 1024),
          16, 0, 0);
    }
  }

  // A fragments: contiguous 16B/lane from tiled rep
  int itile0 = ig * 16 + wave * 2;
  const unsigned short* Ap =
      A + (size_t)b * 131072 + (size_t)itile0 * 512 + h * 256 + p * 8;
  short8v af0 = *(const short8v*)(const void*)(Ap);
  short8v af1 = *(const short8v*)(const void*)(Ap + 512);

  f32x16 zero;
  #pragma unroll
  for (int i = 0; i < 16; ++i) zero[i] = 0.0f;
  f32x16 mrow0, mrow1;
  #pragma unroll
  for (int i = 0; i < 16; ++i) { mrow0[i] = -3.4e38f; mrow1[i] = -3.4e38f; }

  __syncthreads();   // drains global_load_lds + barrier

  const char* sBb = (const char*)sB + h * 512 + p * 16;   // lane's frag base

  #pragma unroll 1
  for (int jt = 0; jt < JTILES; jt += 2) {
    short8v u0 = *(const short8v*)(const void*)(sBb + (size_t)jt * 1024);
    short8v u1 = *(const short8v*)(const void*)(sBb + (size_t)jt * 1024 + 1024);
    {
      f32x16 acc0 = __builtin_amdgcn_mfma_f32_32x32x16_bf16(af0, u0, zero, 0, 0, 0);
      f32x16 acc1 = __builtin_amdgcn_mfma_f32_32x32x16_bf16(af0, u1, zero, 0, 0, 0);
      #pragma unroll
      for (int r = 0; r < 16; ++r)
        mrow0[r] = fmaxf(fmaxf(acc0[r], acc1[r]), mrow0[r]);   // v_max3
    }
    {
      f32x16 acc0 = __builtin_amdgcn_mfma_f32_32x32x16_bf16(af1, u0, zero, 0, 0, 0);
      f32x16 acc1 = __builtin_amdgcn_mfma_f32_32x32x16_bf16(af1, u1, zero, 0, 0, 0);
      #pragma unroll
      for (int r = 0; r < 16; ++r)
        mrow1[r] = fmaxf(fmaxf(acc0[r], acc1[r]), mrow1[r]);   // v_max3
    }
  }

  // reduce over the 32 columns held across lanes of each half
  #pragma unroll
  for (int r = 0; r < 16; ++r) {
    float v0 = mrow0[r], v1 = mrow1[r];
    #pragma unroll
    for (int sh = 1; sh <= 16; sh <<= 1) {
      v0 = fmaxf(v0, __shfl_xor(v0, sh, 64));
      v1 = fmaxf(v1, __shfl_xor(v1, sh, 64));
    }
    mrow0[r] = v0; mrow1[r] = v1;
  }
  if (p == 0) {
    unsigned* rb = rowbuf + ((size_t)dir * BATCH + b) * NPTS + ig * 512 + wave * 64;
    #pragma unroll
    for (int r = 0; r < 16; ++r) {
      int row = (r & 3) + 8 * (r >> 2) + 4 * h;   // verified 32x32 C/D map
      atomicMax(rb + row, enc_f32(mrow0[r]));     // NJ=8 contenders, idempotent
      atomicMax(rb + 32 + row, enc_f32(mrow1[r]));
    }
  }
}

__global__ __launch_bounds__(1024) void loss_final(
    const unsigned* __restrict__ rowbuf, float* __restrict__ out) {
  int tid = threadIdx.x;
  const uint4* rb4 = (const uint4*)rowbuf;   // 16384 uint4
  float s = 0.0f;
  #pragma unroll
  for (int k = 0; k < NSLOTS / 4096; ++k) {  // 16 iters
    uint4 u = rb4[k * 1024 + tid];
    s = fmaf(-2.0f, dec_f32(u.x), s);
    s = fmaf(-2.0f, dec_f32(u.y), s);
    s = fmaf(-2.0f, dec_f32(u.z), s);
    s = fmaf(-2.0f, dec_f32(u.w), s);
  }
  #pragma unroll
  for (int off = 32; off > 0; off >>= 1) s += __shfl_down(s, off, 64);
  __shared__ float wsum[16];
  if ((tid & 63) == 0) wsum[tid >> 6] = s;
  __syncthreads();
  if (tid == 0) {
    float t = 0.0f;
    #pragma unroll
    for (int w2 = 0; w2 < 16; ++w2) t += wsum[w2];
    out[0] = t;
  }
}

extern "C" void kernel_launch(void* const* d_in, const int* in_sizes, int n_in,
                              void* d_out, int out_size, void* d_ws, size_t ws_size,
                              hipStream_t stream) {
  const float* c1 = (const float*)d_in[0];
  const float* c2 = (const float*)d_in[1];
  float* out = (float*)d_out;

  char* ws = (char*)d_ws;
  unsigned* rowbuf = (unsigned*)ws;                          // 65536 u32 = 256 KB
  unsigned short* a1 = (unsigned short*)(ws + (size_t)NSLOTS * 4);
  unsigned short* a2 = a1 + (size_t)BATCH * NPTS * 16;       // 1 MB each
  unsigned short* b1 = a2 + (size_t)BATCH * NPTS * 16;
  unsigned short* b2 = b1 + (size_t)BATCH * NPTS * 16;

  prep<<<(BATCH * NPTS) / 256, 256, 0, stream>>>(c1, c2, a1, a2, b1, b2, rowbuf);
  // Launched twice (idempotent atomicMax) to measure main-kernel duration
  // from total: main = (total - ~11us) / 2.
  chamfer_mfma<<<2 * BATCH * 16 * NJ, 512, 0, stream>>>(a1, a2, b1, b2, rowbuf);
  chamfer_mfma<<<2 * BATCH * 16 * NJ, 512, 0, stream>>>(a1, a2, b1, b2, rowbuf);
  loss_final<<<1, 1024, 0, stream>>>(rowbuf, out);
}